// Round 5
// baseline (312.895 us; speedup 1.0000x reference)
//
#include <hip/hip_runtime.h>
#include <math.h>

#define NSIG   1023
#define BATCH  16
#define FT     1024          // F_BINS == T == 1024
#define KW     320           // truncated window taps, d in [-160, 159]
#define RHALF  160
#define XPAD   1344          // 160 + 1023 + 159 (+2 pad to mult of 4)
#define HID    128

// ws layout (float offsets)
#define OFF_XCP  0u                       // 16*1344 = 21504
#define OFF_G    21504u                   // 320
#define OFF_HRAW 21824u                   // 2048  (fc1 accum, b-major: b*128+j)
#define OFF_TAB  23872u                   // bf16 hi/lo tables, 4 x 327680 u16
// u16 offsets within tab
#define TAB_ECH  0u
#define TAB_ECL  327680u
#define TAB_ESH  655360u
#define TAB_ESL  983040u
// y split tables (big-ws path): u16 [b][t][320], hi and lo
#define OFF_YH   679232u                  // float units
#define OFF_YL   3300672u
#define WS_NEED  23688448ull              // bytes required for y tables path

typedef int   i32x4 __attribute__((ext_vector_type(4)));
typedef float f32x4 __attribute__((ext_vector_type(4)));
typedef unsigned short u16;

static __device__ __forceinline__ unsigned bfbits(float v) {
    unsigned u = __builtin_bit_cast(unsigned, v);
    return (u + 0x7fffu + ((u >> 16) & 1u)) >> 16;   // RNE round to bf16
}

// ---------------- K0: per-batch mean removal into zero-padded buffer ----------
__global__ void k_prep(const float* __restrict__ x, float* __restrict__ ws) {
    int b = blockIdx.x;
    __shared__ float red[256];
    float s = 0.f;
    for (int i = threadIdx.x; i < NSIG; i += 256) s += x[b * NSIG + i];
    red[threadIdx.x] = s;
    __syncthreads();
    for (int o = 128; o > 0; o >>= 1) {
        if (threadIdx.x < o) red[threadIdx.x] += red[threadIdx.x + o];
        __syncthreads();
    }
    float mean = red[0] * (1.0f / NSIG);
    float* xcp = ws + OFF_XCP + b * XPAD;
    for (int i = threadIdx.x; i < XPAD; i += 256) {
        int n = i - RHALF;
        xcp[i] = (n >= 0 && n < NSIG) ? (x[b * NSIG + n] - mean) : 0.f;
    }
}

// ---------------- K1: hi/lo bf16 sincos tables, f-major [f][320] --------------
__global__ void k_tables(const float* __restrict__ lambd, float* __restrict__ ws) {
    int bid = blockIdx.x;
    if (bid == 1280) {
        float sigma = fabsf(lambd[0]);
        float inv2s2 = 0.5f / (sigma * sigma);
        for (int i = threadIdx.x; i < KW; i += 256) {
            float d = (float)(i - RHALF);
            ws[OFF_G + i] = expf(-d * d * inv2s2);
        }
        for (int i = threadIdx.x; i < 2048; i += 256) ws[OFF_HRAW + i] = 0.f;
        return;
    }
    int idx = bid * 256 + threadIdx.x;       // 0 .. 327679 = f*320 + k
    int f = idx / 320, k = idx - f * 320;
    int d = k - RHALF;
    int p = f * d;                           // |p| <= 163680, fits int
    int m = p % 2046; if (m < 0) m += 2046;  // exact phase mod 2pi
    double ang = (double)m * (6.283185307179586476925286766559 / 2046.0);
    double sv, cv;
    sincos(ang, &sv, &cv);
    float cf = (float)cv, sf = (float)sv;
    u16* tab = (u16*)(ws + OFF_TAB);
    unsigned chb = bfbits(cf);
    float chf = __builtin_bit_cast(float, chb << 16);
    unsigned clb = bfbits(cf - chf);
    unsigned shb = bfbits(sf);
    float shf = __builtin_bit_cast(float, shb << 16);
    unsigned slb = bfbits(sf - shf);
    tab[TAB_ECH + idx] = (u16)chb;
    tab[TAB_ECL + idx] = (u16)clb;
    tab[TAB_ESH + idx] = (u16)shb;
    tab[TAB_ESL + idx] = (u16)slb;
}

// ---------------- K1b: precompute y = xc*g split into bf16 hi/lo --------------
// grid (16 t-tiles, 16 b) x 256. Layout u16 [b][t][320] (row 640 B, 16-aligned).
__global__ void k_ysplit(float* __restrict__ ws) {
    int t0 = blockIdx.x * 64, b = blockIdx.y;
    __shared__ float xseg[384];
    __shared__ float gsh[KW];
    const float* xcp = ws + OFF_XCP + b * XPAD;
    int tid = threadIdx.x;
    if (tid < 96) *(float4*)&xseg[tid * 4] = *(const float4*)&xcp[t0 + tid * 4];
    if (tid >= 96 && tid < 176) {
        int i = (tid - 96) * 4;
        *(float4*)&gsh[i] = *(const float4*)&ws[OFF_G + i];
    }
    __syncthreads();
    int tl = tid >> 2;           // 0..63 local t
    int kq = tid & 3;            // 0..3  k-phase (coalesced 64B groups)
    u16* yHp = (u16*)(ws + OFF_YH) + (size_t)b * 327680 + (size_t)(t0 + tl) * 320;
    u16* yLp = (u16*)(ws + OFF_YL) + (size_t)b * 327680 + (size_t)(t0 + tl) * 320;
    for (int i = 0; i < 10; i++) {
        int k = (kq + i * 4) * 8;
        unsigned hb[8], lb[8];
        #pragma unroll
        for (int j = 0; j < 8; j++) {
            float y = xseg[tl + k + j] * gsh[k + j];
            unsigned u = __builtin_bit_cast(unsigned, y);
            unsigned h = (u + 0x7fffu + ((u >> 16) & 1u)) & 0xffff0000u;
            float hf = __builtin_bit_cast(float, h);
            hb[j] = h >> 16;
            lb[j] = bfbits(y - hf);
        }
        i32x4 ph, pl;
        ph.x = (int)(hb[0] | (hb[1] << 16)); ph.y = (int)(hb[2] | (hb[3] << 16));
        ph.z = (int)(hb[4] | (hb[5] << 16)); ph.w = (int)(hb[6] | (hb[7] << 16));
        pl.x = (int)(lb[0] | (lb[1] << 16)); pl.y = (int)(lb[2] | (lb[3] << 16));
        pl.z = (int)(lb[4] | (lb[5] << 16)); pl.w = (int)(lb[6] | (lb[7] << 16));
        *(i32x4*)(yHp + k) = ph;
        *(i32x4*)(yLp + k) = pl;
    }
}

// ---------------- K2 (big-ws): spectrogram MFMA, y precomputed ----------------
// grid (16 t, 16 f, 16 b), 4 waves; wave owns 16-row f-strip, loops 4 t-tiles.
// Per 32-k chunk: stage y hi/lo (4 KB each) into double-buffered swizzled LDS,
// direct-load A fragments (L2-resident tables), 24 MFMA. One barrier/chunk.
__global__ __launch_bounds__(256, 4) void k_spec2(const float* __restrict__ ws,
                                                  float* __restrict__ out) {
    __shared__ u16 yHs[2][2048];
    __shared__ u16 yLs[2][2048];
    int t0 = blockIdx.x * 64, f0 = blockIdx.y * 64, b = blockIdx.z;
    int tid = threadIdx.x;
    int wave = tid >> 6, lane = tid & 63;
    int lo = lane & 15, hi4 = lane >> 4;
    const u16* tab = (const u16*)(ws + OFF_TAB);

    // staging mapping: thread -> (t = tid&63, kgroup = tid>>6)
    int ts = tid & 63, kg = tid >> 6;
    const u16* ygH = (const u16*)(ws + OFF_YH) + (size_t)b * 327680
                   + (size_t)(t0 + ts) * 320 + kg * 8;
    const u16* ygL = (const u16*)(ws + OFF_YL) + (size_t)b * 327680
                   + (size_t)(t0 + ts) * 320 + kg * 8;
    int wb = ((ts * 64 + kg * 16) ^ ((ts & 6) << 3));   // swizzled byte addr

    size_t arow = (size_t)(f0 + wave * 16 + lo) * 320 + hi4 * 8;
    const u16* pech = tab + TAB_ECH + arow;
    const u16* pecl = tab + TAB_ECL + arow;
    const u16* pesh = tab + TAB_ESH + arow;
    const u16* pesl = tab + TAB_ESL + arow;

    f32x4 reA[4], imA[4];
    #pragma unroll
    for (int i = 0; i < 4; i++) {
        reA[i] = (f32x4){0.f, 0.f, 0.f, 0.f};
        imA[i] = (f32x4){0.f, 0.f, 0.f, 0.f};
    }

    // prologue: stage chunk 0 into buf 0
    {
        i32x4 sh = *(const i32x4*)ygH;
        i32x4 sl = *(const i32x4*)ygL;
        *(i32x4*)((char*)yHs[0] + wb) = sh;
        *(i32x4*)((char*)yLs[0] + wb) = sl;
    }
    __syncthreads();

    for (int c = 0; c < 10; c++) {
        i32x4 nh, nl;
        if (c < 9) {                               // issue next-chunk loads early
            nh = *(const i32x4*)(ygH + (c + 1) * 32);
            nl = *(const i32x4*)(ygL + (c + 1) * 32);
        }
        i32x4 ech = *(const i32x4*)(pech + c * 32);
        i32x4 ecl = *(const i32x4*)(pecl + c * 32);
        i32x4 esh = *(const i32x4*)(pesh + c * 32);
        i32x4 esl = *(const i32x4*)(pesl + c * 32);
        const u16* bufH = yHs[c & 1];
        const u16* bufL = yLs[c & 1];
        #pragma unroll
        for (int tt = 0; tt < 4; tt++) {
            int tr = tt * 16 + lo;
            int rb = ((tr * 64 + hi4 * 16) ^ ((tr & 6) << 3));
            i32x4 yh = *(const i32x4*)((const char*)bufH + rb);
            i32x4 yl = *(const i32x4*)((const char*)bufL + rb);
            asm("v_mfma_f32_16x16x32_bf16 %0, %1, %2, %0" : "+v"(reA[tt]) : "v"(ech), "v"(yh));
            asm("v_mfma_f32_16x16x32_bf16 %0, %1, %2, %0" : "+v"(imA[tt]) : "v"(esh), "v"(yh));
            asm("v_mfma_f32_16x16x32_bf16 %0, %1, %2, %0" : "+v"(reA[tt]) : "v"(ech), "v"(yl));
            asm("v_mfma_f32_16x16x32_bf16 %0, %1, %2, %0" : "+v"(imA[tt]) : "v"(esh), "v"(yl));
            asm("v_mfma_f32_16x16x32_bf16 %0, %1, %2, %0" : "+v"(reA[tt]) : "v"(ecl), "v"(yh));
            asm("v_mfma_f32_16x16x32_bf16 %0, %1, %2, %0" : "+v"(imA[tt]) : "v"(esl), "v"(yh));
        }
        if (c < 9) {                               // write-late (data now arrived)
            *(i32x4*)((char*)yHs[(c + 1) & 1] + wb) = nh;
            *(i32x4*)((char*)yLs[(c + 1) & 1] + wb) = nl;
        }
        __syncthreads();
    }
    asm volatile("s_nop 7\n\ts_nop 7");   // MFMA->VALU read hazard guard

    float* dS = out + 160;
    #pragma unroll
    for (int tt = 0; tt < 4; tt++) {
        #pragma unroll
        for (int r = 0; r < 4; r++) {
            int f = f0 + wave * 16 + hi4 * 4 + r;
            float re = reA[tt][r], im = imA[tt][r];
            dS[((size_t)b << 20) + (size_t)f * 1024 + t0 + tt * 16 + lo] = re * re + im * im;
        }
    }
}

// ---------------- K2 (fallback, small ws): R4 kernel, in-loop split -----------
__global__ __launch_bounds__(256, 4) void k_spec1(const float* __restrict__ ws,
                                                  float* __restrict__ out) {
    __shared__ float xseg[384];
    __shared__ float gsh[KW];
    __shared__ u16 yH[2048];
    __shared__ u16 yL[2048];

    int t0 = blockIdx.x * 64, f0 = blockIdx.y * 64, b = blockIdx.z;
    int tid = threadIdx.x;
    int wave = tid >> 6, lane = tid & 63;
    int lo = lane & 15, hi4 = lane >> 4;
    const float* xcp = ws + OFF_XCP + b * XPAD;
    const u16* tab = (const u16*)(ws + OFF_TAB);

    if (tid < 96) *(float4*)&xseg[tid * 4] = *(const float4*)&xcp[t0 + tid * 4];
    if (tid >= 96 && tid < 176) {
        int i = (tid - 96) * 4;
        *(float4*)&gsh[i] = *(const float4*)&ws[OFF_G + i];
    }

    size_t arow = (size_t)(f0 + wave * 16 + lo) * 320 + hi4 * 8;
    const u16* pech = tab + TAB_ECH + arow;
    const u16* pecl = tab + TAB_ECL + arow;
    const u16* pesh = tab + TAB_ESH + arow;
    const u16* pesl = tab + TAB_ESL + arow;

    f32x4 reA[4], imA[4];
    #pragma unroll
    for (int i = 0; i < 4; i++) {
        reA[i] = (f32x4){0.f, 0.f, 0.f, 0.f};
        imA[i] = (f32x4){0.f, 0.f, 0.f, 0.f};
    }

    int ty = tid & 63, kgq = tid >> 6;
    int waddr = ((ty * 64 + kgq * 16) ^ ((ty & 3) << 5));

    __syncthreads();

    for (int k0 = 0; k0 < KW; k0 += 32) {
        {
            int kb = k0 + kgq * 8;
            unsigned hb[8], lb[8];
            #pragma unroll
            for (int j = 0; j < 8; j++) {
                float y = xseg[ty + kb + j] * gsh[kb + j];
                unsigned u = __builtin_bit_cast(unsigned, y);
                unsigned h = (u + 0x7fffu + ((u >> 16) & 1u)) & 0xffff0000u;
                float hf = __builtin_bit_cast(float, h);
                float l = y - hf;
                hb[j] = h >> 16;
                lb[j] = bfbits(l);
            }
            i32x4 ph, pl;
            ph.x = (int)(hb[0] | (hb[1] << 16)); ph.y = (int)(hb[2] | (hb[3] << 16));
            ph.z = (int)(hb[4] | (hb[5] << 16)); ph.w = (int)(hb[6] | (hb[7] << 16));
            pl.x = (int)(lb[0] | (lb[1] << 16)); pl.y = (int)(lb[2] | (lb[3] << 16));
            pl.z = (int)(lb[4] | (lb[5] << 16)); pl.w = (int)(lb[6] | (lb[7] << 16));
            *(i32x4*)((char*)yH + waddr) = ph;
            *(i32x4*)((char*)yL + waddr) = pl;
        }
        __syncthreads();

        i32x4 ech = *(const i32x4*)pech;
        i32x4 ecl = *(const i32x4*)pecl;
        i32x4 esh = *(const i32x4*)pesh;
        i32x4 esl = *(const i32x4*)pesl;
        pech += 32; pecl += 32; pesh += 32; pesl += 32;

        #pragma unroll
        for (int tt = 0; tt < 4; tt++) {
            int tr = tt * 16 + lo;
            int raddr = ((tr * 64 + hi4 * 16) ^ ((tr & 3) << 5));
            i32x4 yh = *(const i32x4*)((char*)yH + raddr);
            i32x4 yl = *(const i32x4*)((char*)yL + raddr);
            asm("v_mfma_f32_16x16x32_bf16 %0, %1, %2, %0" : "+v"(reA[tt]) : "v"(ech), "v"(yh));
            asm("v_mfma_f32_16x16x32_bf16 %0, %1, %2, %0" : "+v"(imA[tt]) : "v"(esh), "v"(yh));
            asm("v_mfma_f32_16x16x32_bf16 %0, %1, %2, %0" : "+v"(reA[tt]) : "v"(ech), "v"(yl));
            asm("v_mfma_f32_16x16x32_bf16 %0, %1, %2, %0" : "+v"(imA[tt]) : "v"(esh), "v"(yl));
            asm("v_mfma_f32_16x16x32_bf16 %0, %1, %2, %0" : "+v"(reA[tt]) : "v"(ecl), "v"(yh));
            asm("v_mfma_f32_16x16x32_bf16 %0, %1, %2, %0" : "+v"(imA[tt]) : "v"(esl), "v"(yh));
        }
        __syncthreads();
    }
    asm volatile("s_nop 7\n\ts_nop 7");

    float* dS = out + 160;
    #pragma unroll
    for (int tt = 0; tt < 4; tt++) {
        #pragma unroll
        for (int r = 0; r < 4; r++) {
            int f = f0 + wave * 16 + hi4 * 4 + r;
            float re = reA[tt][r], im = imA[tt][r];
            dS[((size_t)b << 20) + (size_t)f * 1024 + t0 + tt * 16 + lo] = re * re + im * im;
        }
    }
}

// ---------------- K3: fc1 via MFMA split-K, single S read ---------------------
// 512 blocks x 4 waves; wave ks = blockIdx*4+wave owns one 512-k stripe and all
// 128 j (8 j-tiles). Pack via v_cvt_pk_bf16_f32 (RNE, 1 instr / 2 floats).
static __device__ __forceinline__ i32x4 pack8cvt(float4 a, float4 b) {
    i32x4 r;
    asm("v_cvt_pk_bf16_f32 %0, %1, %2" : "=v"(r.x) : "v"(a.x), "v"(a.y));
    asm("v_cvt_pk_bf16_f32 %0, %1, %2" : "=v"(r.y) : "v"(a.z), "v"(a.w));
    asm("v_cvt_pk_bf16_f32 %0, %1, %2" : "=v"(r.z) : "v"(b.x), "v"(b.y));
    asm("v_cvt_pk_bf16_f32 %0, %1, %2" : "=v"(r.w) : "v"(b.z), "v"(b.w));
    return r;
}

__global__ __launch_bounds__(256, 2) void k_fc1(const float* __restrict__ S,
                                                const float* __restrict__ W1,
                                                float* __restrict__ hraw) {
    __shared__ float red[4][2048];
    int tid = threadIdx.x;
    int wave = tid >> 6, lane = tid & 63;
    int ks = (blockIdx.x << 2) | wave;           // 0..2047 k-stripe
    int bq = lane >> 4, lo = lane & 15;

    const float* Sp = S + (size_t)lo * (1u << 20) + (size_t)ks * 512 + bq * 8;
    const float* Wp = W1 + (size_t)lo * (1u << 20) + (size_t)ks * 512 + bq * 8;

    f32x4 acc[8];
    #pragma unroll
    for (int j = 0; j < 8; j++) acc[j] = (f32x4){0.f, 0.f, 0.f, 0.f};

    for (int step = 0; step < 16; step++) {
        const float* sp = Sp + step * 32;
        float4 a0 = *(const float4*)(sp);
        float4 a1 = *(const float4*)(sp + 4);
        i32x4 af = pack8cvt(a0, a1);
        #pragma unroll
        for (int jt = 0; jt < 8; jt++) {
            const float* wp = Wp + (size_t)jt * (16u << 20) + step * 32;
            float4 w0 = *(const float4*)(wp);
            float4 w1 = *(const float4*)(wp + 4);
            i32x4 bf = pack8cvt(w0, w1);
            asm("v_mfma_f32_16x16x32_bf16 %0, %1, %2, %0" : "+v"(acc[jt]) : "v"(af), "v"(bf));
        }
    }
    asm volatile("s_nop 7\n\ts_nop 7");   // MFMA->VALU read hazard guard

    // red[wave][b*128 + j], b = bq*4+r, j = jt*16+lo
    #pragma unroll
    for (int jt = 0; jt < 8; jt++) {
        #pragma unroll
        for (int r = 0; r < 4; r++) {
            red[wave][(bq * 4 + r) * 128 + jt * 16 + lo] = acc[jt][r];
        }
    }
    __syncthreads();
    for (int p = tid; p < 2048; p += 256) {
        float v = red[0][p] + red[1][p] + red[2][p] + red[3][p];
        atomicAdd(&hraw[p], v);
    }
}

// ---------------- K4: bias+relu+fc2 head --------------------------------------
__global__ void k_head(const float* __restrict__ hraw, const float* __restrict__ b1,
                       const float* __restrict__ W2, const float* __restrict__ b2,
                       float* __restrict__ out) {
    __shared__ float hl[2048];
    int tid = threadIdx.x;
    for (int p = tid; p < 2048; p += 256) {
        float hv = hraw[p] + b1[p & 127];
        hl[p] = hv > 0.f ? hv : 0.f;
    }
    __syncthreads();
    if (tid < 160) {
        int b = tid / 10, c = tid - b * 10;
        float s = b2[c];
        for (int j = 0; j < 128; j++) s += hl[b * 128 + j] * W2[c * 128 + j];
        out[b * 10 + c] = s;
    }
}

extern "C" void kernel_launch(void* const* d_in, const int* in_sizes, int n_in,
                              void* d_out, int out_size, void* d_ws, size_t ws_size,
                              hipStream_t stream) {
    const float* x     = (const float*)d_in[0];
    const float* lambd = (const float*)d_in[1];
    const float* W1    = (const float*)d_in[2];
    const float* b1    = (const float*)d_in[3];
    const float* W2    = (const float*)d_in[4];
    const float* b2    = (const float*)d_in[5];
    float* out = (float*)d_out;
    float* ws  = (float*)d_ws;

    hipLaunchKernelGGL(k_prep,   dim3(16),   dim3(256), 0, stream, x, ws);
    hipLaunchKernelGGL(k_tables, dim3(1281), dim3(256), 0, stream, lambd, ws);
    if (ws_size >= WS_NEED) {
        hipLaunchKernelGGL(k_ysplit, dim3(16, 16),     dim3(256), 0, stream, ws);
        hipLaunchKernelGGL(k_spec2,  dim3(16, 16, 16), dim3(256), 0, stream, ws, out);
    } else {
        hipLaunchKernelGGL(k_spec1,  dim3(16, 16, 16), dim3(256), 0, stream, ws, out);
    }
    hipLaunchKernelGGL(k_fc1,    dim3(512),  dim3(256), 0, stream,
                       out + 160, W1, ws + OFF_HRAW);
    hipLaunchKernelGGL(k_head,   dim3(1),    dim3(256), 0, stream,
                       ws + OFF_HRAW, b1, W2, b2, out);
}

// Round 6
// 256.464 us; speedup vs baseline: 1.2200x; 1.2200x over previous
//
#include <hip/hip_runtime.h>
#include <math.h>

#define NSIG   1023
#define BATCH  16
#define FT     1024          // F_BINS == T == 1024
#define KW     256           // truncated window taps, d in [-128, 127] (4 sigma)
#define RHALF  128
#define XPAD   1280          // 128 + 1023 + 127 (+2 pad)
#define HID    128

// ws layout (float offsets)
#define OFF_XCP  0u                       // 16*1280 = 20480
#define OFF_G    20480u                   // 256
#define OFF_HRAW 20736u                   // 2048  (fc1 accum, b-major: b*128+j)
#define OFF_TAB  22784u                   // bf16 hi/lo tables, 4 x 262144 u16
// u16 offsets within tab (f-major [f][256])
#define TAB_ECH  0u
#define TAB_ECL  262144u
#define TAB_ESH  524288u
#define TAB_ESL  786432u

typedef int   i32x4 __attribute__((ext_vector_type(4)));
typedef float f32x4 __attribute__((ext_vector_type(4)));
typedef unsigned short u16;

static __device__ __forceinline__ unsigned bfbits(float v) {
    unsigned u = __builtin_bit_cast(unsigned, v);
    return (u + 0x7fffu + ((u >> 16) & 1u)) >> 16;   // RNE round to bf16
}

// ---------------- K0: per-batch mean removal into zero-padded buffer ----------
__global__ void k_prep(const float* __restrict__ x, float* __restrict__ ws) {
    int b = blockIdx.x;
    __shared__ float red[256];
    float s = 0.f;
    for (int i = threadIdx.x; i < NSIG; i += 256) s += x[b * NSIG + i];
    red[threadIdx.x] = s;
    __syncthreads();
    for (int o = 128; o > 0; o >>= 1) {
        if (threadIdx.x < o) red[threadIdx.x] += red[threadIdx.x + o];
        __syncthreads();
    }
    float mean = red[0] * (1.0f / NSIG);
    float* xcp = ws + OFF_XCP + b * XPAD;
    for (int i = threadIdx.x; i < XPAD; i += 256) {
        int n = i - RHALF;
        xcp[i] = (n >= 0 && n < NSIG) ? (x[b * NSIG + n] - mean) : 0.f;
    }
}

// ---------------- K1: hi/lo bf16 sincos tables, f-major [f][256] --------------
__global__ void k_tables(const float* __restrict__ lambd, float* __restrict__ ws) {
    int bid = blockIdx.x;
    if (bid == 1024) {
        float sigma = fabsf(lambd[0]);
        float inv2s2 = 0.5f / (sigma * sigma);
        for (int i = threadIdx.x; i < KW; i += 256) {
            float d = (float)(i - RHALF);
            ws[OFF_G + i] = expf(-d * d * inv2s2);
        }
        for (int i = threadIdx.x; i < 2048; i += 256) ws[OFF_HRAW + i] = 0.f;
        return;
    }
    int idx = bid * 256 + threadIdx.x;       // 0 .. 262143 = f*256 + k
    int f = idx >> 8, k = idx & 255;
    int d = k - RHALF;
    int p = f * d;                           // |p| <= 130944, fits int
    int m = p % 2046; if (m < 0) m += 2046;  // exact phase mod 2pi
    double ang = (double)m * (6.283185307179586476925286766559 / 2046.0);
    double sv, cv;
    sincos(ang, &sv, &cv);
    float cf = (float)cv, sf = (float)sv;
    u16* tab = (u16*)(ws + OFF_TAB);
    unsigned chb = bfbits(cf);
    float chf = __builtin_bit_cast(float, chb << 16);
    unsigned clb = bfbits(cf - chf);
    unsigned shb = bfbits(sf);
    float shf = __builtin_bit_cast(float, shb << 16);
    unsigned slb = bfbits(sf - shf);
    tab[TAB_ECH + idx] = (u16)chb;
    tab[TAB_ECL + idx] = (u16)clb;
    tab[TAB_ESH + idx] = (u16)shb;
    tab[TAB_ESL + idx] = (u16)slb;
}

// ---------------- K2: spectrogram MFMA, full-y-in-LDS, barrier-free loop ------
// grid (16 t, 8 f, 16 b), 512 threads = 8 waves. Per block: 64 t x 128 f.
// Stage y=xc*g hi/lo split ONCE (64t x 256k, 64 KB LDS, XOR-swizzled), one
// barrier, then 8 K-chunks of pure {A-loads(L2) + ds_read_b128 + 24 MFMA}.
// Split product: Ah*Bh + Ah*Bl + Al*Bh (lo*lo dropped, rel err ~2^-18).
__global__ __launch_bounds__(512, 4) void k_spec(const float* __restrict__ ws,
                                                 float* __restrict__ out) {
    __shared__ u16 yH[64 * 256];   // 32 KB, swizzled [t][256]
    __shared__ u16 yL[64 * 256];   // 32 KB
    int t0 = blockIdx.x * 64, f0 = blockIdx.y * 128, b = blockIdx.z;
    int tid = threadIdx.x;
    int wave = tid >> 6, lane = tid & 63;
    int lo = lane & 15, hi4 = lane >> 4;
    const u16* tab = (const u16*)(ws + OFF_TAB);
    const float* xcp = ws + OFF_XCP + b * XPAD;
    const float* gw  = ws + OFF_G;

    // ---- one-time staging: 2048 groups of 8 k-consecutive elems ----
    #pragma unroll
    for (int i = 0; i < 4; i++) {
        int idx = tid + i * 512;             // 0..2047
        int t = idx >> 5, kg = idx & 31;
        int k = kg * 8;
        const float* xp = xcp + t0 + t + k;
        float4 g0 = *(const float4*)&gw[k];
        float4 g1 = *(const float4*)&gw[k + 4];
        float yv[8];
        yv[0] = xp[0] * g0.x; yv[1] = xp[1] * g0.y;
        yv[2] = xp[2] * g0.z; yv[3] = xp[3] * g0.w;
        yv[4] = xp[4] * g1.x; yv[5] = xp[5] * g1.y;
        yv[6] = xp[6] * g1.z; yv[7] = xp[7] * g1.w;
        unsigned hb[8], lb[8];
        #pragma unroll
        for (int j = 0; j < 8; j++) {
            unsigned u = __builtin_bit_cast(unsigned, yv[j]);
            unsigned h = (u + 0x7fffu + ((u >> 16) & 1u)) & 0xffff0000u;
            float hf = __builtin_bit_cast(float, h);
            hb[j] = h >> 16;
            lb[j] = bfbits(yv[j] - hf);
        }
        i32x4 ph, pl;
        ph.x = (int)(hb[0] | (hb[1] << 16)); ph.y = (int)(hb[2] | (hb[3] << 16));
        ph.z = (int)(hb[4] | (hb[5] << 16)); ph.w = (int)(hb[6] | (hb[7] << 16));
        pl.x = (int)(lb[0] | (lb[1] << 16)); pl.y = (int)(lb[2] | (lb[3] << 16));
        pl.z = (int)(lb[4] | (lb[5] << 16)); pl.w = (int)(lb[6] | (lb[7] << 16));
        int wb = ((t * 512 + kg * 16) ^ ((t & 7) << 4));
        *(i32x4*)((char*)yH + wb) = ph;
        *(i32x4*)((char*)yL + wb) = pl;
    }
    __syncthreads();

    // ---- A-fragment pointers: row f = f0 + wave*16 + lo, 8 k at hi4*8 ----
    size_t arow = (size_t)(f0 + wave * 16 + lo) * 256 + hi4 * 8;
    const u16* pech = tab + TAB_ECH + arow;
    const u16* pecl = tab + TAB_ECL + arow;
    const u16* pesh = tab + TAB_ESH + arow;
    const u16* pesl = tab + TAB_ESL + arow;

    f32x4 reA[4], imA[4];
    #pragma unroll
    for (int i = 0; i < 4; i++) {
        reA[i] = (f32x4){0.f, 0.f, 0.f, 0.f};
        imA[i] = (f32x4){0.f, 0.f, 0.f, 0.f};
    }

    // ---- barrier-free main loop: 8 chunks x 24 MFMA ----
    #pragma unroll 2
    for (int c = 0; c < 8; c++) {
        i32x4 ech = *(const i32x4*)(pech + c * 32);
        i32x4 ecl = *(const i32x4*)(pecl + c * 32);
        i32x4 esh = *(const i32x4*)(pesh + c * 32);
        i32x4 esl = *(const i32x4*)(pesl + c * 32);
        #pragma unroll
        for (int tt = 0; tt < 4; tt++) {
            int tr = tt * 16 + lo;
            int rb = ((tr * 512 + c * 64 + hi4 * 16) ^ ((tr & 7) << 4));
            i32x4 yh = *(const i32x4*)((const char*)yH + rb);
            i32x4 yl = *(const i32x4*)((const char*)yL + rb);
            asm("v_mfma_f32_16x16x32_bf16 %0, %1, %2, %0" : "+v"(reA[tt]) : "v"(ech), "v"(yh));
            asm("v_mfma_f32_16x16x32_bf16 %0, %1, %2, %0" : "+v"(imA[tt]) : "v"(esh), "v"(yh));
            asm("v_mfma_f32_16x16x32_bf16 %0, %1, %2, %0" : "+v"(reA[tt]) : "v"(ech), "v"(yl));
            asm("v_mfma_f32_16x16x32_bf16 %0, %1, %2, %0" : "+v"(imA[tt]) : "v"(esh), "v"(yl));
            asm("v_mfma_f32_16x16x32_bf16 %0, %1, %2, %0" : "+v"(reA[tt]) : "v"(ecl), "v"(yh));
            asm("v_mfma_f32_16x16x32_bf16 %0, %1, %2, %0" : "+v"(imA[tt]) : "v"(esl), "v"(yh));
        }
    }
    asm volatile("s_nop 7\n\ts_nop 7");   // MFMA->VALU read hazard guard

    // ---- epilogue: S = re^2 + im^2; C layout col=lane&15(t), row=hi4*4+r(f) --
    float* dS = out + 160;
    #pragma unroll
    for (int tt = 0; tt < 4; tt++) {
        #pragma unroll
        for (int r = 0; r < 4; r++) {
            int f = f0 + wave * 16 + hi4 * 4 + r;
            float re = reA[tt][r], im = imA[tt][r];
            dS[((size_t)b << 20) + (size_t)f * 1024 + t0 + tt * 16 + lo] = re * re + im * im;
        }
    }
}

// ---------------- K3: fc1 via MFMA split-K (R4-proven) ------------------------
static __device__ __forceinline__ int packbf2(float a, float b) {
    return (int)(bfbits(a) | (bfbits(b) << 16));
}
static __device__ __forceinline__ i32x4 pack8(float4 a, float4 b) {
    i32x4 r;
    r.x = packbf2(a.x, a.y); r.y = packbf2(a.z, a.w);
    r.z = packbf2(b.x, b.y); r.w = packbf2(b.z, b.w);
    return r;
}

__global__ __launch_bounds__(256, 4) void k_fc1(const float* __restrict__ S,
                                                const float* __restrict__ W1,
                                                float* __restrict__ hraw) {
    __shared__ float red[4][1024];
    int tid = threadIdx.x;
    int wave = tid >> 6, lane = tid & 63;
    int jg = wave >> 1;                          // 0..1 : j-half
    int ks = (blockIdx.x << 1) | (wave & 1);     // 0..2047 k-stripe
    int bq = lane >> 4, lo = lane & 15;

    const float* Sp = S + (size_t)lo * (1u << 20) + (size_t)ks * 512 + bq * 8;
    const float* Wp = W1 + (size_t)(jg * 64 + lo) * (1u << 20) + (size_t)ks * 512 + bq * 8;

    f32x4 acc0 = {0.f,0.f,0.f,0.f}, acc1 = acc0, acc2 = acc0, acc3 = acc0;

    for (int step = 0; step < 16; step++) {
        const float* sp = Sp + step * 32;
        const float* wp = Wp + step * 32;
        float4 a0 = *(const float4*)(sp);
        float4 a1 = *(const float4*)(sp + 4);
        float4 w00 = *(const float4*)(wp);
        float4 w01 = *(const float4*)(wp + 4);
        float4 w10 = *(const float4*)(wp + (1u << 24));          // +16 rows * 1M
        float4 w11 = *(const float4*)(wp + (1u << 24) + 4);
        float4 w20 = *(const float4*)(wp + (2u << 24));
        float4 w21 = *(const float4*)(wp + (2u << 24) + 4);
        float4 w30 = *(const float4*)(wp + (3u << 24));
        float4 w31 = *(const float4*)(wp + (3u << 24) + 4);
        i32x4 af = pack8(a0, a1);
        i32x4 b0 = pack8(w00, w01);
        i32x4 b1 = pack8(w10, w11);
        i32x4 b2 = pack8(w20, w21);
        i32x4 b3 = pack8(w30, w31);
        asm("v_mfma_f32_16x16x32_bf16 %0, %1, %2, %0" : "+v"(acc0) : "v"(af), "v"(b0));
        asm("v_mfma_f32_16x16x32_bf16 %0, %1, %2, %0" : "+v"(acc1) : "v"(af), "v"(b1));
        asm("v_mfma_f32_16x16x32_bf16 %0, %1, %2, %0" : "+v"(acc2) : "v"(af), "v"(b2));
        asm("v_mfma_f32_16x16x32_bf16 %0, %1, %2, %0" : "+v"(acc3) : "v"(af), "v"(b3));
    }
    asm volatile("s_nop 7\n\ts_nop 7");   // MFMA->VALU read hazard guard

    #pragma unroll
    for (int r = 0; r < 4; r++) {
        red[wave][(bq * 4 + r) * 64 +  0 + lo] = acc0[r];
        red[wave][(bq * 4 + r) * 64 + 16 + lo] = acc1[r];
        red[wave][(bq * 4 + r) * 64 + 32 + lo] = acc2[r];
        red[wave][(bq * 4 + r) * 64 + 48 + lo] = acc3[r];
    }
    __syncthreads();
    for (int p = tid; p < 2048; p += 256) {
        int g = p >> 10, idx = p & 1023;
        float v = red[g * 2][idx] + red[g * 2 + 1][idx];
        atomicAdd(&hraw[(idx >> 6) * HID + g * 64 + (idx & 63)], v);
    }
}

// ---------------- K4: bias+relu+fc2 head --------------------------------------
__global__ void k_head(const float* __restrict__ hraw, const float* __restrict__ b1,
                       const float* __restrict__ W2, const float* __restrict__ b2,
                       float* __restrict__ out) {
    __shared__ float hl[2048];
    int tid = threadIdx.x;
    for (int p = tid; p < 2048; p += 256) {
        float hv = hraw[p] + b1[p & 127];
        hl[p] = hv > 0.f ? hv : 0.f;
    }
    __syncthreads();
    if (tid < 160) {
        int b = tid / 10, c = tid - b * 10;
        float s = b2[c];
        for (int j = 0; j < 128; j++) s += hl[b * 128 + j] * W2[c * 128 + j];
        out[b * 10 + c] = s;
    }
}

extern "C" void kernel_launch(void* const* d_in, const int* in_sizes, int n_in,
                              void* d_out, int out_size, void* d_ws, size_t ws_size,
                              hipStream_t stream) {
    const float* x     = (const float*)d_in[0];
    const float* lambd = (const float*)d_in[1];
    const float* W1    = (const float*)d_in[2];
    const float* b1    = (const float*)d_in[3];
    const float* W2    = (const float*)d_in[4];
    const float* b2    = (const float*)d_in[5];
    float* out = (float*)d_out;
    float* ws  = (float*)d_ws;

    hipLaunchKernelGGL(k_prep,   dim3(16),         dim3(256), 0, stream, x, ws);
    hipLaunchKernelGGL(k_tables, dim3(1025),       dim3(256), 0, stream, lambd, ws);
    hipLaunchKernelGGL(k_spec,   dim3(16, 8, 16),  dim3(512), 0, stream, ws, out);
    hipLaunchKernelGGL(k_fc1,    dim3(1024),       dim3(256), 0, stream,
                       out + 160, W1, ws + OFF_HRAW);
    hipLaunchKernelGGL(k_head,   dim3(1),          dim3(256), 0, stream,
                       ws + OFF_HRAW, b1, W2, b2, out);
}

// Round 7
// 240.242 us; speedup vs baseline: 1.3024x; 1.0675x over previous
//
#include <hip/hip_runtime.h>
#include <math.h>

#define NSIG   1023
#define BATCH  16
#define FT     1024          // F_BINS == T == 1024
#define KW     256           // truncated window taps, d in [-128, 127] (4 sigma)
#define RHALF  128
#define XPAD   1280          // 128 + 1023 + 127 (+2 pad)
#define HID    128

// ws layout (float offsets)
#define OFF_XCP  0u                       // 16*1280 = 20480
#define OFF_G    20480u                   // 256
#define OFF_HRAW 20736u                   // 2048  (fc1 accum, b-major: b*128+j)
#define OFF_TAB  22784u                   // bf16 hi/lo tables, 4 x 262144 u16
// u16 offsets within tab (f-major [f][256])
#define TAB_ECH  0u
#define TAB_ECL  262144u
#define TAB_ESH  524288u
#define TAB_ESL  786432u

typedef int   i32x4 __attribute__((ext_vector_type(4)));
typedef float f32x4 __attribute__((ext_vector_type(4)));
typedef unsigned short u16;

static __device__ __forceinline__ unsigned bfbits(float v) {
    unsigned u = __builtin_bit_cast(unsigned, v);
    return (u + 0x7fffu + ((u >> 16) & 1u)) >> 16;   // RNE round to bf16
}

// ---------------- K0: per-batch mean removal into zero-padded buffer ----------
__global__ void k_prep(const float* __restrict__ x, float* __restrict__ ws) {
    int b = blockIdx.x;
    __shared__ float red[256];
    float s = 0.f;
    for (int i = threadIdx.x; i < NSIG; i += 256) s += x[b * NSIG + i];
    red[threadIdx.x] = s;
    __syncthreads();
    for (int o = 128; o > 0; o >>= 1) {
        if (threadIdx.x < o) red[threadIdx.x] += red[threadIdx.x + o];
        __syncthreads();
    }
    float mean = red[0] * (1.0f / NSIG);
    float* xcp = ws + OFF_XCP + b * XPAD;
    for (int i = threadIdx.x; i < XPAD; i += 256) {
        int n = i - RHALF;
        xcp[i] = (n >= 0 && n < NSIG) ? (x[b * NSIG + n] - mean) : 0.f;
    }
}

// ---------------- K1: hi/lo bf16 sincos tables, f-major [f][256] --------------
__global__ void k_tables(const float* __restrict__ lambd, float* __restrict__ ws) {
    int bid = blockIdx.x;
    if (bid == 1024) {
        float sigma = fabsf(lambd[0]);
        float inv2s2 = 0.5f / (sigma * sigma);
        for (int i = threadIdx.x; i < KW; i += 256) {
            float d = (float)(i - RHALF);
            ws[OFF_G + i] = expf(-d * d * inv2s2);
        }
        for (int i = threadIdx.x; i < 2048; i += 256) ws[OFF_HRAW + i] = 0.f;
        return;
    }
    int idx = bid * 256 + threadIdx.x;       // 0 .. 262143 = f*256 + k
    int f = idx >> 8, k = idx & 255;
    int d = k - RHALF;
    int p = f * d;                           // |p| <= 130944, fits int
    int m = p % 2046; if (m < 0) m += 2046;  // exact phase mod 2pi
    double ang = (double)m * (6.283185307179586476925286766559 / 2046.0);
    double sv, cv;
    sincos(ang, &sv, &cv);
    float cf = (float)cv, sf = (float)sv;
    u16* tab = (u16*)(ws + OFF_TAB);
    unsigned chb = bfbits(cf);
    float chf = __builtin_bit_cast(float, chb << 16);
    unsigned clb = bfbits(cf - chf);
    unsigned shb = bfbits(sf);
    float shf = __builtin_bit_cast(float, shb << 16);
    unsigned slb = bfbits(sf - shf);
    tab[TAB_ECH + idx] = (u16)chb;
    tab[TAB_ECL + idx] = (u16)clb;
    tab[TAB_ESH + idx] = (u16)shb;
    tab[TAB_ESL + idx] = (u16)slb;
}

// ---------------- K2: spectrogram MFMA, full-y-in-LDS, barrier-free loop ------
// (unchanged from R6 — measured ~34 us, near MFMA/LDS bound)
__global__ __launch_bounds__(512, 4) void k_spec(const float* __restrict__ ws,
                                                 float* __restrict__ out) {
    __shared__ u16 yH[64 * 256];   // 32 KB, swizzled [t][256]
    __shared__ u16 yL[64 * 256];   // 32 KB
    int t0 = blockIdx.x * 64, f0 = blockIdx.y * 128, b = blockIdx.z;
    int tid = threadIdx.x;
    int wave = tid >> 6, lane = tid & 63;
    int lo = lane & 15, hi4 = lane >> 4;
    const u16* tab = (const u16*)(ws + OFF_TAB);
    const float* xcp = ws + OFF_XCP + b * XPAD;
    const float* gw  = ws + OFF_G;

    #pragma unroll
    for (int i = 0; i < 4; i++) {
        int idx = tid + i * 512;             // 0..2047
        int t = idx >> 5, kg = idx & 31;
        int k = kg * 8;
        const float* xp = xcp + t0 + t + k;
        float4 g0 = *(const float4*)&gw[k];
        float4 g1 = *(const float4*)&gw[k + 4];
        float yv[8];
        yv[0] = xp[0] * g0.x; yv[1] = xp[1] * g0.y;
        yv[2] = xp[2] * g0.z; yv[3] = xp[3] * g0.w;
        yv[4] = xp[4] * g1.x; yv[5] = xp[5] * g1.y;
        yv[6] = xp[6] * g1.z; yv[7] = xp[7] * g1.w;
        unsigned hb[8], lb[8];
        #pragma unroll
        for (int j = 0; j < 8; j++) {
            unsigned u = __builtin_bit_cast(unsigned, yv[j]);
            unsigned h = (u + 0x7fffu + ((u >> 16) & 1u)) & 0xffff0000u;
            float hf = __builtin_bit_cast(float, h);
            hb[j] = h >> 16;
            lb[j] = bfbits(yv[j] - hf);
        }
        i32x4 ph, pl;
        ph.x = (int)(hb[0] | (hb[1] << 16)); ph.y = (int)(hb[2] | (hb[3] << 16));
        ph.z = (int)(hb[4] | (hb[5] << 16)); ph.w = (int)(hb[6] | (hb[7] << 16));
        pl.x = (int)(lb[0] | (lb[1] << 16)); pl.y = (int)(lb[2] | (lb[3] << 16));
        pl.z = (int)(lb[4] | (lb[5] << 16)); pl.w = (int)(lb[6] | (lb[7] << 16));
        int wb = ((t * 512 + kg * 16) ^ ((t & 7) << 4));
        *(i32x4*)((char*)yH + wb) = ph;
        *(i32x4*)((char*)yL + wb) = pl;
    }
    __syncthreads();

    size_t arow = (size_t)(f0 + wave * 16 + lo) * 256 + hi4 * 8;
    const u16* pech = tab + TAB_ECH + arow;
    const u16* pecl = tab + TAB_ECL + arow;
    const u16* pesh = tab + TAB_ESH + arow;
    const u16* pesl = tab + TAB_ESL + arow;

    f32x4 reA[4], imA[4];
    #pragma unroll
    for (int i = 0; i < 4; i++) {
        reA[i] = (f32x4){0.f, 0.f, 0.f, 0.f};
        imA[i] = (f32x4){0.f, 0.f, 0.f, 0.f};
    }

    #pragma unroll 2
    for (int c = 0; c < 8; c++) {
        i32x4 ech = *(const i32x4*)(pech + c * 32);
        i32x4 ecl = *(const i32x4*)(pecl + c * 32);
        i32x4 esh = *(const i32x4*)(pesh + c * 32);
        i32x4 esl = *(const i32x4*)(pesl + c * 32);
        #pragma unroll
        for (int tt = 0; tt < 4; tt++) {
            int tr = tt * 16 + lo;
            int rb = ((tr * 512 + c * 64 + hi4 * 16) ^ ((tr & 7) << 4));
            i32x4 yh = *(const i32x4*)((const char*)yH + rb);
            i32x4 yl = *(const i32x4*)((const char*)yL + rb);
            asm("v_mfma_f32_16x16x32_bf16 %0, %1, %2, %0" : "+v"(reA[tt]) : "v"(ech), "v"(yh));
            asm("v_mfma_f32_16x16x32_bf16 %0, %1, %2, %0" : "+v"(imA[tt]) : "v"(esh), "v"(yh));
            asm("v_mfma_f32_16x16x32_bf16 %0, %1, %2, %0" : "+v"(reA[tt]) : "v"(ech), "v"(yl));
            asm("v_mfma_f32_16x16x32_bf16 %0, %1, %2, %0" : "+v"(imA[tt]) : "v"(esh), "v"(yl));
            asm("v_mfma_f32_16x16x32_bf16 %0, %1, %2, %0" : "+v"(reA[tt]) : "v"(ecl), "v"(yh));
            asm("v_mfma_f32_16x16x32_bf16 %0, %1, %2, %0" : "+v"(imA[tt]) : "v"(esl), "v"(yh));
        }
    }
    asm volatile("s_nop 7\n\ts_nop 7");   // MFMA->VALU read hazard guard

    float* dS = out + 160;
    #pragma unroll
    for (int tt = 0; tt < 4; tt++) {
        #pragma unroll
        for (int r = 0; r < 4; r++) {
            int f = f0 + wave * 16 + hi4 * 4 + r;
            float re = reA[tt][r], im = imA[tt][r];
            dS[((size_t)b << 20) + (size_t)f * 1024 + t0 + tt * 16 + lo] = re * re + im * im;
        }
    }
}

// ---------------- K3: fc1 via MFMA split-K, low-VGPR / high-occupancy ---------
// h[b,j] = sum_i S[b,i] * W1[j,i]. 1024 blocks x 4 waves as R4/R6, but the
// inner loop holds only one W float4-pair live (load->pack->MFMA per j-tile)
// and __launch_bounds__(256,6) caps VGPR ~84 -> 24 waves/CU (was 16).
static __device__ __forceinline__ int packbf2(float a, float b) {
    return (int)(bfbits(a) | (bfbits(b) << 16));
}
static __device__ __forceinline__ i32x4 pack8(float4 a, float4 b) {
    i32x4 r;
    r.x = packbf2(a.x, a.y); r.y = packbf2(a.z, a.w);
    r.z = packbf2(b.x, b.y); r.w = packbf2(b.z, b.w);
    return r;
}

__global__ __launch_bounds__(256, 6) void k_fc1(const float* __restrict__ S,
                                                const float* __restrict__ W1,
                                                float* __restrict__ hraw) {
    __shared__ float red[4][1024];
    int tid = threadIdx.x;
    int wave = tid >> 6, lane = tid & 63;
    int jg = wave >> 1;                          // 0..1 : j-half
    int ks = (blockIdx.x << 1) | (wave & 1);     // 0..2047 k-stripe
    int bq = lane >> 4, lo = lane & 15;

    const float* Sp = S + (size_t)lo * (1u << 20) + (size_t)ks * 512 + bq * 8;
    const float* Wp = W1 + (size_t)(jg * 64 + lo) * (1u << 20) + (size_t)ks * 512 + bq * 8;

    f32x4 acc0 = {0.f,0.f,0.f,0.f}, acc1 = acc0, acc2 = acc0, acc3 = acc0;

    for (int step = 0; step < 16; step++) {
        const float* sp = Sp + step * 32;
        const float* wp = Wp + step * 32;
        float4 a0 = *(const float4*)(sp);
        float4 a1 = *(const float4*)(sp + 4);
        i32x4 af = pack8(a0, a1);
        {
            float4 w0 = *(const float4*)(wp);
            float4 w1 = *(const float4*)(wp + 4);
            i32x4 bf = pack8(w0, w1);
            asm("v_mfma_f32_16x16x32_bf16 %0, %1, %2, %0" : "+v"(acc0) : "v"(af), "v"(bf));
        }
        {
            float4 w0 = *(const float4*)(wp + (1u << 24));
            float4 w1 = *(const float4*)(wp + (1u << 24) + 4);
            i32x4 bf = pack8(w0, w1);
            asm("v_mfma_f32_16x16x32_bf16 %0, %1, %2, %0" : "+v"(acc1) : "v"(af), "v"(bf));
        }
        {
            float4 w0 = *(const float4*)(wp + (2u << 24));
            float4 w1 = *(const float4*)(wp + (2u << 24) + 4);
            i32x4 bf = pack8(w0, w1);
            asm("v_mfma_f32_16x16x32_bf16 %0, %1, %2, %0" : "+v"(acc2) : "v"(af), "v"(bf));
        }
        {
            float4 w0 = *(const float4*)(wp + (3u << 24));
            float4 w1 = *(const float4*)(wp + (3u << 24) + 4);
            i32x4 bf = pack8(w0, w1);
            asm("v_mfma_f32_16x16x32_bf16 %0, %1, %2, %0" : "+v"(acc3) : "v"(af), "v"(bf));
        }
    }
    asm volatile("s_nop 7\n\ts_nop 7");   // MFMA->VALU read hazard guard

    #pragma unroll
    for (int r = 0; r < 4; r++) {
        red[wave][(bq * 4 + r) * 64 +  0 + lo] = acc0[r];
        red[wave][(bq * 4 + r) * 64 + 16 + lo] = acc1[r];
        red[wave][(bq * 4 + r) * 64 + 32 + lo] = acc2[r];
        red[wave][(bq * 4 + r) * 64 + 48 + lo] = acc3[r];
    }
    __syncthreads();
    for (int p = tid; p < 2048; p += 256) {
        int g = p >> 10, idx = p & 1023;
        float v = red[g * 2][idx] + red[g * 2 + 1][idx];
        atomicAdd(&hraw[(idx >> 6) * HID + g * 64 + (idx & 63)], v);
    }
}

// ---------------- K4: bias+relu+fc2 head --------------------------------------
__global__ void k_head(const float* __restrict__ hraw, const float* __restrict__ b1,
                       const float* __restrict__ W2, const float* __restrict__ b2,
                       float* __restrict__ out) {
    __shared__ float hl[2048];
    int tid = threadIdx.x;
    for (int p = tid; p < 2048; p += 256) {
        float hv = hraw[p] + b1[p & 127];
        hl[p] = hv > 0.f ? hv : 0.f;
    }
    __syncthreads();
    if (tid < 160) {
        int b = tid / 10, c = tid - b * 10;
        float s = b2[c];
        for (int j = 0; j < 128; j++) s += hl[b * 128 + j] * W2[c * 128 + j];
        out[b * 10 + c] = s;
    }
}

extern "C" void kernel_launch(void* const* d_in, const int* in_sizes, int n_in,
                              void* d_out, int out_size, void* d_ws, size_t ws_size,
                              hipStream_t stream) {
    const float* x     = (const float*)d_in[0];
    const float* lambd = (const float*)d_in[1];
    const float* W1    = (const float*)d_in[2];
    const float* b1    = (const float*)d_in[3];
    const float* W2    = (const float*)d_in[4];
    const float* b2    = (const float*)d_in[5];
    float* out = (float*)d_out;
    float* ws  = (float*)d_ws;

    hipLaunchKernelGGL(k_prep,   dim3(16),         dim3(256), 0, stream, x, ws);
    hipLaunchKernelGGL(k_tables, dim3(1025),       dim3(256), 0, stream, lambd, ws);
    hipLaunchKernelGGL(k_spec,   dim3(16, 8, 16),  dim3(512), 0, stream, ws, out);
    hipLaunchKernelGGL(k_fc1,    dim3(1024),       dim3(256), 0, stream,
                       out + 160, W1, ws + OFF_HRAW);
    hipLaunchKernelGGL(k_head,   dim3(1),          dim3(256), 0, stream,
                       ws + OFF_HRAW, b1, W2, b2, out);
}